// Round 7
// baseline (513.165 us; speedup 1.0000x reference)
//
#include <hip/hip_runtime.h>

// ---------------------------------------------------------------------------
// Fused TE multihead self-attention w/ NABLA block mask, MI355X (gfx950).
// S=2048, C=2048, H=16, D=128, BLK=64, nb=32, THR=0.8.
//
// Round 7: revert QK to round-5 gemm8_bt (128x128, 8 waves, 2 blocks/CU;
// round-6 256x128 regressed: 1 block/CU killed latency hiding) with compact
// [hi|lo] layout via k-remap. V/O -> new gemm8_n64 (128x64, grid 512,
// 3 blocks/CU, 6 waves/SIMD). Attn: exact defer-rescale. Fused conv launches.
// ---------------------------------------------------------------------------

#define S_LEN 2048
#define CDIM  2048
#define NH    16
#define HD    128
#define NB    32

typedef __attribute__((ext_vector_type(8))) short s8v;   // 8 x bf16 (4 VGPR)
typedef __attribute__((ext_vector_type(4))) short s4v;
typedef __attribute__((ext_vector_type(4))) float f4v;

__device__ __forceinline__ short f2bf(float f){
  unsigned u = __builtin_bit_cast(unsigned, f);
  u += 0x7fffu + ((u>>16)&1u);                 // RNE
  return (short)(u>>16);
}
__device__ __forceinline__ float bf2f(short s){
  unsigned u = ((unsigned)(unsigned short)s)<<16;
  return __builtin_bit_cast(float, u);
}
__device__ __forceinline__ void gload_lds16(const void* g, void* l){
  // async global->LDS, 16B/lane; LDS dest = wave-uniform base + lane*16
  __builtin_amdgcn_global_load_lds(
      (const __attribute__((address_space(1))) void*)g,
      (__attribute__((address_space(3))) void*)l, 16, 0, 0);
}

// ---------------------------------------------------------------------------
// x [S][C] fp32 -> Xcat [S][2C] bf16 : [hi | lo]
// ---------------------------------------------------------------------------
__global__ void __launch_bounds__(256) conv_x_kernel(
    const float* __restrict__ x, short* __restrict__ xcat)
{
  int i = blockIdx.x*256 + threadIdx.x;        // float4 index, 1M total
  f4v v = ((const f4v*)x)[i];
  int s = i >> 9, c4 = (i & 511)*4;
  s4v hi, lo;
#pragma unroll
  for (int e=0;e<4;e++){
    short h = f2bf(v[e]);
    hi[e] = h;
    lo[e] = f2bf(v[e] - bf2f(h));
  }
  short* row = xcat + (size_t)s*4096 + c4;
  *(s4v*)(row)        = hi;
  *(s4v*)(row + 2048) = lo;
}

// ---------------------------------------------------------------------------
// Wq/Wk [K][N] fp32 -> Wcat2^T rows [W_hi | W_lo] bf16; z selects Q/K half.
// ---------------------------------------------------------------------------
__global__ void __launch_bounds__(256) conv_w3_kernel(
    const float* __restrict__ Wq, const float* __restrict__ Wk,
    short* __restrict__ wcat)
{
  __shared__ float tile[64][65];
  const float* W = blockIdx.z ? Wk : Wq;
  short* out = wcat + (size_t)blockIdx.z*2048*4096;
  const int k0 = blockIdx.y*64, n0 = blockIdx.x*64, t = threadIdx.x;
#pragma unroll
  for (int i=0;i<16;i++){
    int idx = i*256 + t, r = idx>>6, c = idx&63;
    tile[r][c] = W[(size_t)(k0+r)*2048 + (n0+c)];
  }
  __syncthreads();
#pragma unroll
  for (int i=0;i<16;i++){
    int idx = i*256 + t, n = idx>>6, k = idx&63;
    float v = tile[k][n];
    short h  = f2bf(v);
    short lo = f2bf(v - bf2f(h));
    short* base = out + (size_t)(n0+n)*4096 + (k0+k);
    base[0]    = h;
    base[2048] = lo;
  }
}

// Wv/Wo [K][N] fp32 -> W^T [N][K] bf16; z selects (Wv->wtv, Wo->wto)
__global__ void __launch_bounds__(256) conv_w1_kernel(
    const float* __restrict__ Wv, const float* __restrict__ Wo,
    short* __restrict__ wtv, short* __restrict__ wto)
{
  __shared__ float tile[64][65];
  const float* W = blockIdx.z ? Wo : Wv;
  short* wt = blockIdx.z ? wto : wtv;
  const int k0 = blockIdx.y*64, n0 = blockIdx.x*64, t = threadIdx.x;
#pragma unroll
  for (int i=0;i<16;i++){
    int idx = i*256 + t, r = idx>>6, c = idx&63;
    tile[r][c] = W[(size_t)(k0+r)*2048 + (n0+c)];
  }
  __syncthreads();
#pragma unroll
  for (int i=0;i<16;i++){
    int idx = i*256 + t, n = idx>>6, k = idx&63;
    wt[(size_t)(n0+n)*2048 + (k0+k)] = f2bf(tile[k][n]);
  }
}

// ---------------------------------------------------------------------------
// 8-wave GEMM (QK): C[M][N] = A @ Bt^T + bias.  128x128 tile, 8 waves
// (2x4 of 64x32), dbuf, vmcnt(4), T2 swizzle.  K-remap for [hi|lo] operands:
// a_off = kt>=awrap ? kt-asub : kt (sim. b).  Grid 1D, %8==0, XCD-bijective.
// ---------------------------------------------------------------------------
template<int OUT>
__global__ void __launch_bounds__(512, 4) gemm8_bt(
    const short* __restrict__ A, int lda,
    const short* __restrict__ Bt, int ldb,
    const float* __restrict__ biasQ, const float* __restrict__ biasK,
    int nsplit,
    void* __restrict__ Cout, int ldc, int K, int ntiles,
    int awrap, int asub, int bwrap, int bsub)
{
  __shared__ short Alds[2][128*64];
  __shared__ short Blds[2][128*64];
  const int t = threadIdx.x, w = t>>6, l = t&63;
  const int nwg = gridDim.x;
  const int bid = blockIdx.x;
  const int swz = (bid & 7)*(nwg>>3) + (bid>>3);   // XCD-bijective (nwg%8==0)
  const int mi = swz / ntiles, ni = swz % ntiles;
  const int m0 = mi*128, n0 = ni*128;
  const int wr = w>>2, wc = w&3;                   // 2x4 waves, 64x32 each
  const int l16 = l&15, lg = l>>4;

  f4v acc[4][2];
  f4v z = {0.f,0.f,0.f,0.f};
#pragma unroll
  for (int a=0;a<4;a++)
#pragma unroll
    for (int b=0;b<2;b++) acc[a][b] = z;

  const int srow = w*16 + (l>>3);
  const int scol = ((l&7) ^ ((l>>3)&7)) * 8;   // shorts (pre-swizzled source)
  const short* Ag = A  + (size_t)(m0 + srow)*lda + scol;
  const short* Bg = Bt + (size_t)(n0 + srow)*ldb + scol;

  auto stageAB = [&](int buf, int kt){
    const int ak = kt - ((kt >= awrap) ? asub : 0);
    const int bk2 = kt - ((kt >= bwrap) ? bsub : 0);
#pragma unroll
    for (int ii=0;ii<2;ii++){
      gload_lds16(Ag + (size_t)ii*8*lda + ak, (char*)Alds[buf] + w*2048 + ii*1024);
      gload_lds16(Bg + (size_t)ii*8*ldb + bk2, (char*)Blds[buf] + w*2048 + ii*1024);
    }
  };

  stageAB(0, 0);
  int cur = 0;
  for (int kt = 0; kt < K; kt += 64){
    if (kt + 64 < K){
      stageAB(cur^1, kt+64);
      asm volatile("s_waitcnt vmcnt(4)" ::: "memory");
    } else {
      asm volatile("s_waitcnt vmcnt(0)" ::: "memory");
    }
    __builtin_amdgcn_s_barrier();
    const char* Al = (const char*)Alds[cur];
    const char* Bl = (const char*)Blds[cur];
#pragma unroll
    for (int kk=0;kk<2;kk++){
      const int swx = ((l16&7)<<4);
      s8v af[4], bfv[2];
#pragma unroll
      for (int mt=0;mt<4;mt++)
        af[mt]  = *(const s8v*)(Al + (wr*64+mt*16+l16)*128 + ((kk*64 + lg*16) ^ swx));
#pragma unroll
      for (int jt=0;jt<2;jt++)
        bfv[jt] = *(const s8v*)(Bl + (wc*32+jt*16+l16)*128 + ((kk*64 + lg*16) ^ swx));
      __builtin_amdgcn_s_setprio(1);
#pragma unroll
      for (int mt=0;mt<4;mt++)
#pragma unroll
        for (int jt=0;jt<2;jt++)
          acc[mt][jt] = __builtin_amdgcn_mfma_f32_16x16x32_bf16(
              af[mt], bfv[jt], acc[mt][jt], 0, 0, 0);
      __builtin_amdgcn_s_setprio(0);
    }
    asm volatile("" ::: "memory");
    __builtin_amdgcn_s_barrier();
    cur ^= 1;
  }

  const float* bp = (n0 >= nsplit) ? (biasK + (n0 - nsplit)) : (biasQ + n0);
#pragma unroll
  for (int mt=0;mt<4;mt++)
#pragma unroll
    for (int r=0;r<4;r++){
      int row = m0 + wr*64 + mt*16 + lg*4 + r;
#pragma unroll
      for (int jt=0;jt<2;jt++){
        int cr = wc*32 + jt*16 + l16;
        float v = acc[mt][jt][r] + bp[cr];
        if (OUT == 0) ((float*)Cout)[(size_t)row*ldc + n0 + cr] = v;
        else          ((short*)Cout)[(size_t)row*ldc + n0 + cr] = f2bf(v);
      }
    }
}

// ---------------------------------------------------------------------------
// 8-wave GEMM (V/O): 128x64 tile, 8 waves (2x4 of 64x16), dbuf, vmcnt(3),
// T2 swizzle.  48KB LDS -> 3 blocks/CU = 6 waves/SIMD.  Grid 1D %8==0.
// ---------------------------------------------------------------------------
template<int OUT>
__global__ void __launch_bounds__(512, 6) gemm8_n64(
    const short* __restrict__ A, int lda,
    const short* __restrict__ Bt, int ldb,
    const float* __restrict__ bias,
    void* __restrict__ Cout, int ldc, int K, int ntiles)
{
  __shared__ short Alds[2][128*64];   // 16 KB each
  __shared__ short Blds[2][64*64];    //  8 KB each
  const int t = threadIdx.x, w = t>>6, l = t&63;
  const int nwg = gridDim.x;
  const int bid = blockIdx.x;
  const int swz = (bid & 7)*(nwg>>3) + (bid>>3);
  const int mi = swz / ntiles, ni = swz % ntiles;
  const int m0 = mi*128, n0 = ni*64;
  const int wr = w>>2, wc = w&3;                   // 2x4 waves, 64x16 each
  const int l16 = l&15, lg = l>>4;

  f4v acc[4];
  f4v z = {0.f,0.f,0.f,0.f};
#pragma unroll
  for (int a=0;a<4;a++) acc[a] = z;

  const int srA = w*16 + (l>>3);                   // A: 16 rows/wave (2 issues)
  const int srB = w*8  + (l>>3);                   // B:  8 rows/wave (1 issue)
  const int scol = ((l&7) ^ ((l>>3)&7)) * 8;
  const short* Ag = A  + (size_t)(m0 + srA)*lda + scol;
  const short* Bg = Bt + (size_t)(n0 + srB)*ldb + scol;

  auto stageAB = [&](int buf, int kt){
#pragma unroll
    for (int ii=0;ii<2;ii++)
      gload_lds16(Ag + (size_t)ii*8*lda + kt, (char*)Alds[buf] + w*2048 + ii*1024);
    gload_lds16(Bg + kt, (char*)Blds[buf] + w*1024);
  };

  stageAB(0, 0);
  int cur = 0;
  for (int kt = 0; kt < K; kt += 64){
    if (kt + 64 < K){
      stageAB(cur^1, kt+64);
      asm volatile("s_waitcnt vmcnt(3)" ::: "memory");
    } else {
      asm volatile("s_waitcnt vmcnt(0)" ::: "memory");
    }
    __builtin_amdgcn_s_barrier();
    const char* Al = (const char*)Alds[cur];
    const char* Bl = (const char*)Blds[cur];
#pragma unroll
    for (int kk=0;kk<2;kk++){
      const int swx = ((l16&7)<<4);
      s8v af[4], bfv;
#pragma unroll
      for (int mt=0;mt<4;mt++)
        af[mt] = *(const s8v*)(Al + (wr*64+mt*16+l16)*128 + ((kk*64 + lg*16) ^ swx));
      bfv = *(const s8v*)(Bl + (wc*16+l16)*128 + ((kk*64 + lg*16) ^ swx));
      __builtin_amdgcn_s_setprio(1);
#pragma unroll
      for (int mt=0;mt<4;mt++)
        acc[mt] = __builtin_amdgcn_mfma_f32_16x16x32_bf16(af[mt], bfv, acc[mt], 0,0,0);
      __builtin_amdgcn_s_setprio(0);
    }
    asm volatile("" ::: "memory");
    __builtin_amdgcn_s_barrier();
    cur ^= 1;
  }

#pragma unroll
  for (int mt=0;mt<4;mt++)
#pragma unroll
    for (int r=0;r<4;r++){
      int row = m0 + wr*64 + mt*16 + lg*4 + r;
      int cr = wc*16 + l16;
      float v = acc[mt][r] + bias[n0 + cr];
      if (OUT == 0) ((float*)Cout)[(size_t)row*ldc + n0 + cr] = v;
      else          ((short*)Cout)[(size_t)row*ldc + n0 + cr] = f2bf(v);
    }
}

// ---------------------------------------------------------------------------
// RMSNorm + RoPE + block-pool (fp32), emits bf16 head-major q/k + fp32 pooled.
// Reads fused QKf [S][4096]: Q cols 0..2047, K cols 2048..4095.
// ---------------------------------------------------------------------------
__global__ void __launch_bounds__(256) qk_post_kernel(
    const float* __restrict__ QKf,
    const float* __restrict__ qw, const float* __restrict__ kw,
    const float* __restrict__ rc, const float* __restrict__ rs,
    short* __restrict__ Qh, short* __restrict__ Kh,
    float* __restrict__ Qb, float* __restrict__ Kb)
{
  __shared__ float pool[4][128];
  const int sb = blockIdx.x, h = blockIdx.y, which = blockIdx.z;
  const float* in    = QKf + (which ? 2048 : 0);
  const float* wvp   = which ? kw : qw;
  short*       outp  = which ? Kh : Qh;
  float*       poolp = which ? Kb : Qb;
  const int t = threadIdx.x, w = t>>6, l = t&63;
  const int s = sb*64 + w*16 + (l>>2), d0 = (l&3)*32;

  float a[32];
  const f4v* src = (const f4v*)(in + (size_t)s*4096 + h*128 + d0);
#pragma unroll
  for (int i=0;i<8;i++){
    f4v v = src[i];
    a[i*4]=v[0]; a[i*4+1]=v[1]; a[i*4+2]=v[2]; a[i*4+3]=v[3];
  }
  float ss = 0.f;
#pragma unroll
  for (int i=0;i<32;i++) ss += a[i]*a[i];
  ss += __shfl_xor(ss,1); ss += __shfl_xor(ss,2);     // full 128-dim sumsq
  float rstd = 1.0f / sqrtf(ss*(1.0f/128.0f) + 1e-6f);

  const f4v* wv4 = (const f4v*)(wvp + d0);
#pragma unroll
  for (int i=0;i<8;i++){
    f4v wv = wv4[i];
    a[i*4]   *= rstd*wv[0]; a[i*4+1] *= rstd*wv[1];
    a[i*4+2] *= rstd*wv[2]; a[i*4+3] *= rstd*wv[3];
  }
  // RoPE: partner chunk is d0 ^ 64 = lane ^ 2
  float cv[32], sv[32];
  const f4v* cs4 = (const f4v*)(rc + (size_t)s*128 + d0);
  const f4v* sn4 = (const f4v*)(rs + (size_t)s*128 + d0);
#pragma unroll
  for (int i=0;i<8;i++){
    f4v c = cs4[i], sn = sn4[i];
    cv[i*4]=c[0]; cv[i*4+1]=c[1]; cv[i*4+2]=c[2]; cv[i*4+3]=c[3];
    sv[i*4]=sn[0]; sv[i*4+1]=sn[1]; sv[i*4+2]=sn[2]; sv[i*4+3]=sn[3];
  }
  const float sgn = (l&2) ? 1.f : -1.f;        // d<64: -x[d+64]; d>=64: +x[d-64]
#pragma unroll
  for (int i=0;i<32;i++){
    float pv = __shfl_xor(a[i], 2);            // symmetric exchange pre-overwrite
    a[i] = a[i]*cv[i] + sgn*pv*sv[i];
  }
  // bf16 head-major write [H][S][D]
  short* op = outp + ((size_t)h*2048 + s)*128 + d0;
#pragma unroll
  for (int c8=0;c8<8;c8++){
    s4v ob;
#pragma unroll
    for (int e=0;e<4;e++) ob[e] = f2bf(a[c8*4+e]);
    ((s4v*)op)[c8] = ob;
  }
  // block-pool (fp32, pre-bf16 values): reduce over 16 rows of the wave
#pragma unroll
  for (int i=0;i<32;i++){
    a[i] += __shfl_xor(a[i],4);
    a[i] += __shfl_xor(a[i],8);
    a[i] += __shfl_xor(a[i],16);
    a[i] += __shfl_xor(a[i],32);
  }
  if ((l>>2)==0){
#pragma unroll
    for (int i=0;i<32;i++) pool[w][d0+i] = a[i];
  }
  __syncthreads();
  if (t < 128)
    poolp[((size_t)h*32 + sb)*128 + t] =
        (pool[0][t]+pool[1][t]+pool[2][t]+pool[3][t]) * (1.0f/64.0f);
}

// ---------------------------------------------------------------------------
// NABLA mask: pooled softmax + cumulative-density cutoff (sort-free, tie-safe)
// ---------------------------------------------------------------------------
__global__ void __launch_bounds__(64) nabla_mask_kernel(
    const float* __restrict__ Qb, const float* __restrict__ Kb,
    const void* __restrict__ sta, unsigned char* __restrict__ keep)
{
  const int qi = blockIdx.x, h = blockIdx.y, l = threadIdx.x;
  const int j = l & 31;
  const int* si = (const int*)sta;
  int wv0 = si[j];                              // first 128B: safe either dtype
  int isInt = __all((wv0==0) | (wv0==1));

  const f4v* qr = (const f4v*)(Qb + ((size_t)h*32+qi)*128);
  const f4v* kr = (const f4v*)(Kb + ((size_t)h*32+j)*128);
  float dot = 0.f;
#pragma unroll
  for (int d=0; d<32; d++){
    f4v a = qr[d], b = kr[d];
    dot += a[0]*b[0] + a[1]*b[1] + a[2]*b[2] + a[3]*b[3];
  }
  float logit = dot / sqrtf(128.0f);
  float mx = logit;
  mx = fmaxf(mx, __shfl_xor(mx,1));  mx = fmaxf(mx, __shfl_xor(mx,2));
  mx = fmaxf(mx, __shfl_xor(mx,4));  mx = fmaxf(mx, __shfl_xor(mx,8));
  mx = fmaxf(mx, __shfl_xor(mx,16));
  float e = expf(logit - mx);
  float den = e;
  den += __shfl_xor(den,1);  den += __shfl_xor(den,2);
  den += __shfl_xor(den,4);  den += __shfl_xor(den,8);
  den += __shfl_xor(den,16);
  float p = e / den;
  float Sg = 0.f;
  for (int jj=0;jj<32;jj++){
    float pj = __shfl(p, jj);
    if (pj > p) Sg += pj;
  }
  float cand = (Sg < 0.8f) ? p : 3.0e38f;
  float cut = cand;
  cut = fminf(cut, __shfl_xor(cut,1));  cut = fminf(cut, __shfl_xor(cut,2));
  cut = fminf(cut, __shfl_xor(cut,4));  cut = fminf(cut, __shfl_xor(cut,8));
  cut = fminf(cut, __shfl_xor(cut,16));
  bool stab = isInt ? (si[qi*32+j] != 0)
                    : (((const unsigned char*)sta)[qi*32+j] != 0);
  if (l < 32)
    keep[((size_t)(h*32)+qi)*32 + j] = ((p >= cut) || stab) ? 1 : 0;
}

// ---------------------------------------------------------------------------
// v_sd [S][H*D] bf16 -> vt [H][D][S] bf16 (transpose for PV B-operand)
// ---------------------------------------------------------------------------
__global__ void __launch_bounds__(256) v_trans_kernel(
    const short* __restrict__ v_sd, short* __restrict__ vt)
{
  __shared__ short tile[64][65];
  const int sb = blockIdx.x, db = blockIdx.y, h = blockIdx.z, t = threadIdx.x;
#pragma unroll
  for (int i=0;i<16;i++){
    int idx = i*256 + t, r = idx>>6, c = idx&63;
    tile[r][c] = v_sd[(size_t)(sb*64+r)*2048 + h*128 + db*64 + c];
  }
  __syncthreads();
#pragma unroll
  for (int i=0;i<16;i++){
    int idx = i*256 + t, dn = idx>>6, s2 = idx&63;
    vt[((size_t)h*128 + db*64 + dn)*2048 + sb*64 + s2] = tile[s2][dn];
  }
}

// ---------------------------------------------------------------------------
// Block-sparse flash attention (swizzled LDS, dbuf, counted vmcnt, setprio,
// 2 heads/XCD).  Round 7: exact defer-rescale (skip O/lsum rescale when the
// block max doesn't exceed the running max -- resc would be exp(0)=1).
// ---------------------------------------------------------------------------
__global__ void __launch_bounds__(256) attn_fwd_kernel(
    const short* __restrict__ qh, const short* __restrict__ kh,
    const short* __restrict__ vt, const unsigned char* __restrict__ keep,
    short* __restrict__ attn_out)
{
  __shared__ short Klds[2][64*128];   // [buf][kv][d]   16KB each
  __shared__ short Vlds[2][128*64];   // [buf][d][kv]   16KB each
  __shared__ short Plds[4][1024];     // per-wave [16 q][64 kv]  8KB
  const int bid = blockIdx.x;
  const int swz = (bid & 7)*64 + (bid >> 3);
  const int h = swz >> 5, qb = swz & 31;
  const int t = threadIdx.x, w = t>>6, l = t&63;
  const int l16 = l&15, lg = l>>4;

  s8v qf[4];
  const int sq0 = qb*64 + w*16;
  const short* qbase = qh + ((size_t)h*2048 + sq0 + l16)*128 + lg*8;
#pragma unroll
  for (int kf=0;kf<4;kf++) qf[kf] = *(const s8v*)(qbase + kf*32);

  f4v acc[8];
  f4v z = {0.f,0.f,0.f,0.f};
#pragma unroll
  for (int d=0;d<8;d++) acc[d] = z;
  float mrow[4], lsum[4];
#pragma unroll
  for (int r=0;r<4;r++){ mrow[r] = -3.0e38f; lsum[r] = 0.f; }

  const unsigned char* keeprow = keep + ((size_t)(h*32) + qb)*32;
  const short* kg0 = kh + (size_t)h*2048*128;
  const short* vg0 = vt + (size_t)h*128*2048;

  unsigned km = 0;
#pragma unroll
  for (int j=0;j<32;j++) km |= ((unsigned)keeprow[j]) << j;
  if (!km) km = 1;                              // defensive (cannot happen)

  auto stageKV = [&](int buf, int j){
    const char* kg = (const char*)(kg0 + (size_t)(j*64)*128);
    const char* vg = (const char*)(vg0 + j*64);
#pragma unroll
    for (int ii=0;ii<4;ii++){
      int kr = (w*4+ii)*4 + (l>>4);             // K row (256B rows)
      int ks = ((l&15)*16) ^ ((kr&7)<<4);
      gload_lds16(kg + (size_t)kr*256 + ks, (char*)Klds[buf] + (w*4+ii)*1024);
      int vr = (w*4+ii)*8 + (l>>3);             // V row (128B rows, 4096B gstride)
      int vs = ((l&7)*16) ^ ((vr&7)<<4);
      gload_lds16(vg + (size_t)vr*4096 + vs, (char*)Vlds[buf] + (w*4+ii)*1024);
    }
  };

  asm volatile("s_waitcnt vmcnt(0)" ::: "memory");
  int jcur = (int)__builtin_ctz(km); km &= km-1;
  stageKV(0, jcur);
  int cur = 0;

  while (jcur >= 0){
    int jn = -1;
    if (km){ jn = (int)__builtin_ctz(km); km &= km-1; }
    if (jn >= 0){
      stageKV(cur^1, jn);
      asm volatile("s_waitcnt vmcnt(8)" ::: "memory");
    } else {
      asm volatile("s_waitcnt vmcnt(0)" ::: "memory");
    }
    __builtin_amdgcn_s_barrier();

    const char* Kl = (const char*)Klds[cur];
    const char* Vl = (const char*)Vlds[cur];

    f4v sacc[4];
#pragma unroll
    for (int nt=0;nt<4;nt++) sacc[nt] = z;
    __builtin_amdgcn_s_setprio(1);
#pragma unroll
    for (int kf=0;kf<4;kf++)
#pragma unroll
      for (int nt=0;nt<4;nt++){
        int kr = nt*16 + l16;
        s8v bfr = *(const s8v*)(Kl + ((kr*256 + kf*64 + lg*16) ^ ((kr&7)<<4)));
        sacc[nt] = __builtin_amdgcn_mfma_f32_16x16x32_bf16(qf[kf], bfr, sacc[nt], 0,0,0);
      }
    __builtin_amdgcn_s_setprio(0);
    const float scl = 0.08838834764831845f;    // 1/sqrt(128)
#pragma unroll
    for (int nt=0;nt<4;nt++) sacc[nt] *= scl;

#pragma unroll
    for (int r=0;r<4;r++){
      float mx = fmaxf(fmaxf(sacc[0][r], sacc[1][r]),
                       fmaxf(sacc[2][r], sacc[3][r]));
      mx = fmaxf(mx, __shfl_xor(mx,1));  mx = fmaxf(mx, __shfl_xor(mx,2));
      mx = fmaxf(mx, __shfl_xor(mx,4));  mx = fmaxf(mx, __shfl_xor(mx,8));
      if (mx > mrow[r]){                       // exact defer: else resc==1
        float resc = __expf(mrow[r] - mx);
        mrow[r] = mx;
        lsum[r] *= resc;
#pragma unroll
        for (int dt=0;dt<8;dt++) acc[dt][r] *= resc;
      }
      float psum = 0.f;
#pragma unroll
      for (int nt=0;nt<4;nt++){
        float p = __expf(sacc[nt][r] - mrow[r]);
        sacc[nt][r] = p;
        psum += p;
      }
      psum += __shfl_xor(psum,1);  psum += __shfl_xor(psum,2);
      psum += __shfl_xor(psum,4);  psum += __shfl_xor(psum,8);
      lsum[r] += psum;
    }

    char* Pl = (char*)Plds[w];
#pragma unroll
    for (int nt=0;nt<4;nt++)
#pragma unroll
      for (int r=0;r<4;r++){
        int pr = lg*4 + r;                       // P row (128B rows)
        *(short*)(Pl + ((pr*128 + nt*32 + l16*2) ^ ((pr&7)<<4))) = f2bf(sacc[nt][r]);
      }
    s8v pa0 = *(const s8v*)(Pl + ((l16*128 +  0 + lg*16) ^ ((l16&7)<<4)));
    s8v pa1 = *(const s8v*)(Pl + ((l16*128 + 64 + lg*16) ^ ((l16&7)<<4)));

    __builtin_amdgcn_s_setprio(1);
#pragma unroll
    for (int kk=0;kk<2;kk++){
      s8v pa = kk ? pa1 : pa0;
#pragma unroll
      for (int dt=0;dt<8;dt++){
        int vr = dt*16 + l16;
        s8v vb = *(const s8v*)(Vl + ((vr*128 + kk*64 + lg*16) ^ ((vr&7)<<4)));
        acc[dt] = __builtin_amdgcn_mfma_f32_16x16x32_bf16(pa, vb, acc[dt], 0,0,0);
      }
    }
    __builtin_amdgcn_s_setprio(0);

    asm volatile("" ::: "memory");
    __builtin_amdgcn_s_barrier();
    cur ^= 1; jcur = jn;
  }

#pragma unroll
  for (int r=0;r<4;r++){
    float inv = 1.0f / lsum[r];
    int s = qb*64 + w*16 + lg*4 + r;
#pragma unroll
    for (int dt=0;dt<8;dt++)
      attn_out[(size_t)s*2048 + h*128 + dt*16 + l16] = f2bf(acc[dt][r]*inv);
  }
}

// ---------------------------------------------------------------------------
extern "C" void kernel_launch(void* const* d_in, const int* in_sizes, int n_in,
                              void* d_out, int out_size, void* d_ws, size_t ws_size,
                              hipStream_t stream)
{
  (void)in_sizes; (void)n_in; (void)out_size; (void)ws_size;
  const float* x   = (const float*)d_in[0];
  const float* rc  = (const float*)d_in[1];
  const float* rs  = (const float*)d_in[2];
  const void*  sta = d_in[3];
  const float* Wq  = (const float*)d_in[4];
  const float* bq  = (const float*)d_in[5];
  const float* Wk  = (const float*)d_in[6];
  const float* bk  = (const float*)d_in[7];
  const float* Wv  = (const float*)d_in[8];
  const float* bv  = (const float*)d_in[9];
  const float* Wo  = (const float*)d_in[10];
  const float* bo  = (const float*)d_in[11];
  const float* qnw = (const float*)d_in[12];
  const float* knw = (const float*)d_in[13];

  char* ws = (char*)d_ws;
  size_t off = 0;
  auto take = [&](size_t b){ char* p = ws + off; off = (off + b + 255) & ~(size_t)255; return p; };
  short* Xcat  = (short*)take((size_t)2048*4096*2);   // 16.8 MB [hi|lo]
  short* Wcat2 = (short*)take((size_t)4096*4096*2);   // 33.6 MB rows (Q then K)
  short* Wt1v  = (short*)take((size_t)2048*2048*2);   //  8.4 MB
  short* Wt1o  = (short*)take((size_t)2048*2048*2);   //  8.4 MB
  float* QKf   = (float*)take((size_t)2048*4096*4);   // 33.6 MB fused Q|K
  short* Vsd   = (short*)take((size_t)2048*2048*2);   //  8.4 MB
  short* Qh    = (short*)take((size_t)NH*2048*128*2); //  8.4 MB
  short* Kh    = (short*)take((size_t)NH*2048*128*2); //  8.4 MB
  float* Qb    = (float*)take((size_t)NH*32*128*4);
  float* Kb    = (float*)take((size_t)NH*32*128*4);
  unsigned char* Keep = (unsigned char*)take(NH*32*32);
  short* AttnO = (short*)QKf;                          // alias: QKf dead after qk_post
  short* Vt    = (short*)((char*)QKf + (size_t)16*1024*1024);  // alias, disjoint

  conv_x_kernel <<<4096, 256, 0, stream>>>(x, Xcat);
  conv_w3_kernel<<<dim3(32,32,2), 256, 0, stream>>>(Wq, Wk, Wcat2);
  // fused Q+K projection: M=2048, N=4096, logical K=6144 via remap; grid 512
  gemm8_bt<0><<<512, 512, 0, stream>>>(Xcat, 4096, Wcat2, 4096, bq, bk, 2048,
                                       QKf, 4096, 6144, 32,
                                       2048, 2048, 4096, 4096);
  conv_w1_kernel<<<dim3(32,32,2), 256, 0, stream>>>(Wv, Wo, Wt1v, Wt1o);
  gemm8_n64<1><<<512, 512, 0, stream>>>(Xcat, 4096, Wt1v, 2048, bv,
                                        Vsd, 2048, 2048, 32);
  qk_post_kernel<<<dim3(32,16,2), 256, 0, stream>>>(QKf, qnw, knw, rc, rs, Qh, Kh, Qb, Kb);
  v_trans_kernel<<<dim3(32,2,16), 256, 0, stream>>>(Vsd, Vt);
  nabla_mask_kernel<<<dim3(32,16), 64, 0, stream>>>(Qb, Kb, sta, Keep);
  attn_fwd_kernel<<<512, 256, 0, stream>>>(Qh, Kh, Vt, Keep, AttnO);
  gemm8_n64<0><<<512, 512, 0, stream>>>((const short*)AttnO, 2048, Wt1o, 2048, bo,
                                        d_out, 2048, 2048, 32);
}

// Round 8
// 447.196 us; speedup vs baseline: 1.1475x; 1.1475x over previous
//
#include <hip/hip_runtime.h>

// ---------------------------------------------------------------------------
// Fused TE multihead self-attention w/ NABLA block mask, MI355X (gfx950).
// S=2048, C=2048, H=16, D=128, BLK=64, nb=32, THR=0.8.
//
// Round 8: (a) revert round-7 defer-rescale (regressed: VGPR 84->136,
// VALU +50%); (b) attention split-2 over kept KV blocks with flash combine
// -> halves the dense-head straggler and smooths load imbalance (occupancy
// was 10.8%). Partials alias dead Wcat2/Wt1v. GEMMs unchanged.
// ---------------------------------------------------------------------------

#define S_LEN 2048
#define CDIM  2048
#define NH    16
#define HD    128
#define NB    32

typedef __attribute__((ext_vector_type(8))) short s8v;   // 8 x bf16 (4 VGPR)
typedef __attribute__((ext_vector_type(4))) short s4v;
typedef __attribute__((ext_vector_type(4))) float f4v;

__device__ __forceinline__ short f2bf(float f){
  unsigned u = __builtin_bit_cast(unsigned, f);
  u += 0x7fffu + ((u>>16)&1u);                 // RNE
  return (short)(u>>16);
}
__device__ __forceinline__ float bf2f(short s){
  unsigned u = ((unsigned)(unsigned short)s)<<16;
  return __builtin_bit_cast(float, u);
}
__device__ __forceinline__ void gload_lds16(const void* g, void* l){
  // async global->LDS, 16B/lane; LDS dest = wave-uniform base + lane*16
  __builtin_amdgcn_global_load_lds(
      (const __attribute__((address_space(1))) void*)g,
      (__attribute__((address_space(3))) void*)l, 16, 0, 0);
}

// ---------------------------------------------------------------------------
// x [S][C] fp32 -> Xcat [S][2C] bf16 : [hi | lo]
// ---------------------------------------------------------------------------
__global__ void __launch_bounds__(256) conv_x_kernel(
    const float* __restrict__ x, short* __restrict__ xcat)
{
  int i = blockIdx.x*256 + threadIdx.x;        // float4 index, 1M total
  f4v v = ((const f4v*)x)[i];
  int s = i >> 9, c4 = (i & 511)*4;
  s4v hi, lo;
#pragma unroll
  for (int e=0;e<4;e++){
    short h = f2bf(v[e]);
    hi[e] = h;
    lo[e] = f2bf(v[e] - bf2f(h));
  }
  short* row = xcat + (size_t)s*4096 + c4;
  *(s4v*)(row)        = hi;
  *(s4v*)(row + 2048) = lo;
}

// ---------------------------------------------------------------------------
// Wq/Wk [K][N] fp32 -> Wcat2^T rows [W_hi | W_lo] bf16; z selects Q/K half.
// ---------------------------------------------------------------------------
__global__ void __launch_bounds__(256) conv_w3_kernel(
    const float* __restrict__ Wq, const float* __restrict__ Wk,
    short* __restrict__ wcat)
{
  __shared__ float tile[64][65];
  const float* W = blockIdx.z ? Wk : Wq;
  short* out = wcat + (size_t)blockIdx.z*2048*4096;
  const int k0 = blockIdx.y*64, n0 = blockIdx.x*64, t = threadIdx.x;
#pragma unroll
  for (int i=0;i<16;i++){
    int idx = i*256 + t, r = idx>>6, c = idx&63;
    tile[r][c] = W[(size_t)(k0+r)*2048 + (n0+c)];
  }
  __syncthreads();
#pragma unroll
  for (int i=0;i<16;i++){
    int idx = i*256 + t, n = idx>>6, k = idx&63;
    float v = tile[k][n];
    short h  = f2bf(v);
    short lo = f2bf(v - bf2f(h));
    short* base = out + (size_t)(n0+n)*4096 + (k0+k);
    base[0]    = h;
    base[2048] = lo;
  }
}

// Wv/Wo [K][N] fp32 -> W^T [N][K] bf16; z selects (Wv->wtv, Wo->wto)
__global__ void __launch_bounds__(256) conv_w1_kernel(
    const float* __restrict__ Wv, const float* __restrict__ Wo,
    short* __restrict__ wtv, short* __restrict__ wto)
{
  __shared__ float tile[64][65];
  const float* W = blockIdx.z ? Wo : Wv;
  short* wt = blockIdx.z ? wto : wtv;
  const int k0 = blockIdx.y*64, n0 = blockIdx.x*64, t = threadIdx.x;
#pragma unroll
  for (int i=0;i<16;i++){
    int idx = i*256 + t, r = idx>>6, c = idx&63;
    tile[r][c] = W[(size_t)(k0+r)*2048 + (n0+c)];
  }
  __syncthreads();
#pragma unroll
  for (int i=0;i<16;i++){
    int idx = i*256 + t, n = idx>>6, k = idx&63;
    wt[(size_t)(n0+n)*2048 + (k0+k)] = f2bf(tile[k][n]);
  }
}

// ---------------------------------------------------------------------------
// 8-wave GEMM (QK): 128x128 tile, 8 waves (2x4 of 64x32), dbuf, vmcnt(4),
// T2 swizzle, K-remap for [hi|lo] operands.  Grid 1D %8==0, XCD-bijective.
// ---------------------------------------------------------------------------
template<int OUT>
__global__ void __launch_bounds__(512, 4) gemm8_bt(
    const short* __restrict__ A, int lda,
    const short* __restrict__ Bt, int ldb,
    const float* __restrict__ biasQ, const float* __restrict__ biasK,
    int nsplit,
    void* __restrict__ Cout, int ldc, int K, int ntiles,
    int awrap, int asub, int bwrap, int bsub)
{
  __shared__ short Alds[2][128*64];
  __shared__ short Blds[2][128*64];
  const int t = threadIdx.x, w = t>>6, l = t&63;
  const int nwg = gridDim.x;
  const int bid = blockIdx.x;
  const int swz = (bid & 7)*(nwg>>3) + (bid>>3);   // XCD-bijective (nwg%8==0)
  const int mi = swz / ntiles, ni = swz % ntiles;
  const int m0 = mi*128, n0 = ni*128;
  const int wr = w>>2, wc = w&3;                   // 2x4 waves, 64x32 each
  const int l16 = l&15, lg = l>>4;

  f4v acc[4][2];
  f4v z = {0.f,0.f,0.f,0.f};
#pragma unroll
  for (int a=0;a<4;a++)
#pragma unroll
    for (int b=0;b<2;b++) acc[a][b] = z;

  const int srow = w*16 + (l>>3);
  const int scol = ((l&7) ^ ((l>>3)&7)) * 8;   // shorts (pre-swizzled source)
  const short* Ag = A  + (size_t)(m0 + srow)*lda + scol;
  const short* Bg = Bt + (size_t)(n0 + srow)*ldb + scol;

  auto stageAB = [&](int buf, int kt){
    const int ak = kt - ((kt >= awrap) ? asub : 0);
    const int bk2 = kt - ((kt >= bwrap) ? bsub : 0);
#pragma unroll
    for (int ii=0;ii<2;ii++){
      gload_lds16(Ag + (size_t)ii*8*lda + ak, (char*)Alds[buf] + w*2048 + ii*1024);
      gload_lds16(Bg + (size_t)ii*8*ldb + bk2, (char*)Blds[buf] + w*2048 + ii*1024);
    }
  };

  stageAB(0, 0);
  int cur = 0;
  for (int kt = 0; kt < K; kt += 64){
    if (kt + 64 < K){
      stageAB(cur^1, kt+64);
      asm volatile("s_waitcnt vmcnt(4)" ::: "memory");
    } else {
      asm volatile("s_waitcnt vmcnt(0)" ::: "memory");
    }
    __builtin_amdgcn_s_barrier();
    const char* Al = (const char*)Alds[cur];
    const char* Bl = (const char*)Blds[cur];
#pragma unroll
    for (int kk=0;kk<2;kk++){
      const int swx = ((l16&7)<<4);
      s8v af[4], bfv[2];
#pragma unroll
      for (int mt=0;mt<4;mt++)
        af[mt]  = *(const s8v*)(Al + (wr*64+mt*16+l16)*128 + ((kk*64 + lg*16) ^ swx));
#pragma unroll
      for (int jt=0;jt<2;jt++)
        bfv[jt] = *(const s8v*)(Bl + (wc*32+jt*16+l16)*128 + ((kk*64 + lg*16) ^ swx));
      __builtin_amdgcn_s_setprio(1);
#pragma unroll
      for (int mt=0;mt<4;mt++)
#pragma unroll
        for (int jt=0;jt<2;jt++)
          acc[mt][jt] = __builtin_amdgcn_mfma_f32_16x16x32_bf16(
              af[mt], bfv[jt], acc[mt][jt], 0, 0, 0);
      __builtin_amdgcn_s_setprio(0);
    }
    asm volatile("" ::: "memory");
    __builtin_amdgcn_s_barrier();
    cur ^= 1;
  }

  const float* bp = (n0 >= nsplit) ? (biasK + (n0 - nsplit)) : (biasQ + n0);
#pragma unroll
  for (int mt=0;mt<4;mt++)
#pragma unroll
    for (int r=0;r<4;r++){
      int row = m0 + wr*64 + mt*16 + lg*4 + r;
#pragma unroll
      for (int jt=0;jt<2;jt++){
        int cr = wc*32 + jt*16 + l16;
        float v = acc[mt][jt][r] + bp[cr];
        if (OUT == 0) ((float*)Cout)[(size_t)row*ldc + n0 + cr] = v;
        else          ((short*)Cout)[(size_t)row*ldc + n0 + cr] = f2bf(v);
      }
    }
}

// ---------------------------------------------------------------------------
// 8-wave GEMM (V/O): 128x64 tile, 8 waves (2x4 of 64x16), dbuf, vmcnt(3),
// T2 swizzle.  48KB LDS -> 3 blocks/CU = 6 waves/SIMD.  Grid 1D %8==0.
// ---------------------------------------------------------------------------
template<int OUT>
__global__ void __launch_bounds__(512, 6) gemm8_n64(
    const short* __restrict__ A, int lda,
    const short* __restrict__ Bt, int ldb,
    const float* __restrict__ bias,
    void* __restrict__ Cout, int ldc, int K, int ntiles)
{
  __shared__ short Alds[2][128*64];   // 16 KB each
  __shared__ short Blds[2][64*64];    //  8 KB each
  const int t = threadIdx.x, w = t>>6, l = t&63;
  const int nwg = gridDim.x;
  const int bid = blockIdx.x;
  const int swz = (bid & 7)*(nwg>>3) + (bid>>3);
  const int mi = swz / ntiles, ni = swz % ntiles;
  const int m0 = mi*128, n0 = ni*64;
  const int wr = w>>2, wc = w&3;                   // 2x4 waves, 64x16 each
  const int l16 = l&15, lg = l>>4;

  f4v acc[4];
  f4v z = {0.f,0.f,0.f,0.f};
#pragma unroll
  for (int a=0;a<4;a++) acc[a] = z;

  const int srA = w*16 + (l>>3);                   // A: 16 rows/wave (2 issues)
  const int srB = w*8  + (l>>3);                   // B:  8 rows/wave (1 issue)
  const int scol = ((l&7) ^ ((l>>3)&7)) * 8;
  const short* Ag = A  + (size_t)(m0 + srA)*lda + scol;
  const short* Bg = Bt + (size_t)(n0 + srB)*ldb + scol;

  auto stageAB = [&](int buf, int kt){
#pragma unroll
    for (int ii=0;ii<2;ii++)
      gload_lds16(Ag + (size_t)ii*8*lda + kt, (char*)Alds[buf] + w*2048 + ii*1024);
    gload_lds16(Bg + kt, (char*)Blds[buf] + w*1024);
  };

  stageAB(0, 0);
  int cur = 0;
  for (int kt = 0; kt < K; kt += 64){
    if (kt + 64 < K){
      stageAB(cur^1, kt+64);
      asm volatile("s_waitcnt vmcnt(3)" ::: "memory");
    } else {
      asm volatile("s_waitcnt vmcnt(0)" ::: "memory");
    }
    __builtin_amdgcn_s_barrier();
    const char* Al = (const char*)Alds[cur];
    const char* Bl = (const char*)Blds[cur];
#pragma unroll
    for (int kk=0;kk<2;kk++){
      const int swx = ((l16&7)<<4);
      s8v af[4], bfv;
#pragma unroll
      for (int mt=0;mt<4;mt++)
        af[mt] = *(const s8v*)(Al + (wr*64+mt*16+l16)*128 + ((kk*64 + lg*16) ^ swx));
      bfv = *(const s8v*)(Bl + (wc*16+l16)*128 + ((kk*64 + lg*16) ^ swx));
      __builtin_amdgcn_s_setprio(1);
#pragma unroll
      for (int mt=0;mt<4;mt++)
        acc[mt] = __builtin_amdgcn_mfma_f32_16x16x32_bf16(af[mt], bfv, acc[mt], 0,0,0);
      __builtin_amdgcn_s_setprio(0);
    }
    asm volatile("" ::: "memory");
    __builtin_amdgcn_s_barrier();
    cur ^= 1;
  }

#pragma unroll
  for (int mt=0;mt<4;mt++)
#pragma unroll
    for (int r=0;r<4;r++){
      int row = m0 + wr*64 + mt*16 + lg*4 + r;
      int cr = wc*16 + l16;
      float v = acc[mt][r] + bias[n0 + cr];
      if (OUT == 0) ((float*)Cout)[(size_t)row*ldc + n0 + cr] = v;
      else          ((short*)Cout)[(size_t)row*ldc + n0 + cr] = f2bf(v);
    }
}

// ---------------------------------------------------------------------------
// RMSNorm + RoPE + block-pool (fp32), emits bf16 head-major q/k + fp32 pooled.
// ---------------------------------------------------------------------------
__global__ void __launch_bounds__(256) qk_post_kernel(
    const float* __restrict__ QKf,
    const float* __restrict__ qw, const float* __restrict__ kw,
    const float* __restrict__ rc, const float* __restrict__ rs,
    short* __restrict__ Qh, short* __restrict__ Kh,
    float* __restrict__ Qb, float* __restrict__ Kb)
{
  __shared__ float pool[4][128];
  const int sb = blockIdx.x, h = blockIdx.y, which = blockIdx.z;
  const float* in    = QKf + (which ? 2048 : 0);
  const float* wvp   = which ? kw : qw;
  short*       outp  = which ? Kh : Qh;
  float*       poolp = which ? Kb : Qb;
  const int t = threadIdx.x, w = t>>6, l = t&63;
  const int s = sb*64 + w*16 + (l>>2), d0 = (l&3)*32;

  float a[32];
  const f4v* src = (const f4v*)(in + (size_t)s*4096 + h*128 + d0);
#pragma unroll
  for (int i=0;i<8;i++){
    f4v v = src[i];
    a[i*4]=v[0]; a[i*4+1]=v[1]; a[i*4+2]=v[2]; a[i*4+3]=v[3];
  }
  float ss = 0.f;
#pragma unroll
  for (int i=0;i<32;i++) ss += a[i]*a[i];
  ss += __shfl_xor(ss,1); ss += __shfl_xor(ss,2);     // full 128-dim sumsq
  float rstd = 1.0f / sqrtf(ss*(1.0f/128.0f) + 1e-6f);

  const f4v* wv4 = (const f4v*)(wvp + d0);
#pragma unroll
  for (int i=0;i<8;i++){
    f4v wv = wv4[i];
    a[i*4]   *= rstd*wv[0]; a[i*4+1] *= rstd*wv[1];
    a[i*4+2] *= rstd*wv[2]; a[i*4+3] *= rstd*wv[3];
  }
  // RoPE: partner chunk is d0 ^ 64 = lane ^ 2
  float cv[32], sv[32];
  const f4v* cs4 = (const f4v*)(rc + (size_t)s*128 + d0);
  const f4v* sn4 = (const f4v*)(rs + (size_t)s*128 + d0);
#pragma unroll
  for (int i=0;i<8;i++){
    f4v c = cs4[i], sn = sn4[i];
    cv[i*4]=c[0]; cv[i*4+1]=c[1]; cv[i*4+2]=c[2]; cv[i*4+3]=c[3];
    sv[i*4]=sn[0]; sv[i*4+1]=sn[1]; sv[i*4+2]=sn[2]; sv[i*4+3]=sn[3];
  }
  const float sgn = (l&2) ? 1.f : -1.f;        // d<64: -x[d+64]; d>=64: +x[d-64]
#pragma unroll
  for (int i=0;i<32;i++){
    float pv = __shfl_xor(a[i], 2);            // symmetric exchange pre-overwrite
    a[i] = a[i]*cv[i] + sgn*pv*sv[i];
  }
  // bf16 head-major write [H][S][D]
  short* op = outp + ((size_t)h*2048 + s)*128 + d0;
#pragma unroll
  for (int c8=0;c8<8;c8++){
    s4v ob;
#pragma unroll
    for (int e=0;e<4;e++) ob[e] = f2bf(a[c8*4+e]);
    ((s4v*)op)[c8] = ob;
  }
  // block-pool (fp32, pre-bf16 values): reduce over 16 rows of the wave
#pragma unroll
  for (int i=0;i<32;i++){
    a[i] += __shfl_xor(a[i],4);
    a[i] += __shfl_xor(a[i],8);
    a[i] += __shfl_xor(a[i],16);
    a[i] += __shfl_xor(a[i],32);
  }
  if ((l>>2)==0){
#pragma unroll
    for (int i=0;i<32;i++) pool[w][d0+i] = a[i];
  }
  __syncthreads();
  if (t < 128)
    poolp[((size_t)h*32 + sb)*128 + t] =
        (pool[0][t]+pool[1][t]+pool[2][t]+pool[3][t]) * (1.0f/64.0f);
}

// ---------------------------------------------------------------------------
// NABLA mask: pooled softmax + cumulative-density cutoff (sort-free, tie-safe)
// ---------------------------------------------------------------------------
__global__ void __launch_bounds__(64) nabla_mask_kernel(
    const float* __restrict__ Qb, const float* __restrict__ Kb,
    const void* __restrict__ sta, unsigned char* __restrict__ keep)
{
  const int qi = blockIdx.x, h = blockIdx.y, l = threadIdx.x;
  const int j = l & 31;
  const int* si = (const int*)sta;
  int wv0 = si[j];                              // first 128B: safe either dtype
  int isInt = __all((wv0==0) | (wv0==1));

  const f4v* qr = (const f4v*)(Qb + ((size_t)h*32+qi)*128);
  const f4v* kr = (const f4v*)(Kb + ((size_t)h*32+j)*128);
  float dot = 0.f;
#pragma unroll
  for (int d=0; d<32; d++){
    f4v a = qr[d], b = kr[d];
    dot += a[0]*b[0] + a[1]*b[1] + a[2]*b[2] + a[3]*b[3];
  }
  float logit = dot / sqrtf(128.0f);
  float mx = logit;
  mx = fmaxf(mx, __shfl_xor(mx,1));  mx = fmaxf(mx, __shfl_xor(mx,2));
  mx = fmaxf(mx, __shfl_xor(mx,4));  mx = fmaxf(mx, __shfl_xor(mx,8));
  mx = fmaxf(mx, __shfl_xor(mx,16));
  float e = expf(logit - mx);
  float den = e;
  den += __shfl_xor(den,1);  den += __shfl_xor(den,2);
  den += __shfl_xor(den,4);  den += __shfl_xor(den,8);
  den += __shfl_xor(den,16);
  float p = e / den;
  float Sg = 0.f;
  for (int jj=0;jj<32;jj++){
    float pj = __shfl(p, jj);
    if (pj > p) Sg += pj;
  }
  float cand = (Sg < 0.8f) ? p : 3.0e38f;
  float cut = cand;
  cut = fminf(cut, __shfl_xor(cut,1));  cut = fminf(cut, __shfl_xor(cut,2));
  cut = fminf(cut, __shfl_xor(cut,4));  cut = fminf(cut, __shfl_xor(cut,8));
  cut = fminf(cut, __shfl_xor(cut,16));
  bool stab = isInt ? (si[qi*32+j] != 0)
                    : (((const unsigned char*)sta)[qi*32+j] != 0);
  if (l < 32)
    keep[((size_t)(h*32)+qi)*32 + j] = ((p >= cut) || stab) ? 1 : 0;
}

// ---------------------------------------------------------------------------
// v_sd [S][H*D] bf16 -> vt [H][D][S] bf16 (transpose for PV B-operand)
// ---------------------------------------------------------------------------
__global__ void __launch_bounds__(256) v_trans_kernel(
    const short* __restrict__ v_sd, short* __restrict__ vt)
{
  __shared__ short tile[64][65];
  const int sb = blockIdx.x, db = blockIdx.y, h = blockIdx.z, t = threadIdx.x;
#pragma unroll
  for (int i=0;i<16;i++){
    int idx = i*256 + t, r = idx>>6, c = idx&63;
    tile[r][c] = v_sd[(size_t)(sb*64+r)*2048 + h*128 + db*64 + c];
  }
  __syncthreads();
#pragma unroll
  for (int i=0;i<16;i++){
    int idx = i*256 + t, dn = idx>>6, s2 = idx&63;
    vt[((size_t)h*128 + db*64 + dn)*2048 + sb*64 + s2] = tile[s2][dn];
  }
}

// ---------------------------------------------------------------------------
// Block-sparse flash attention, SPLIT-2 over kept KV blocks.
// grid 1024: bid>>9 = part (0/1), inner XCD-swizzled as before.
// Part p processes the even/odd entries of the compacted kept list.
// Writes unnormalized acc + (m,l) partials; combine_kernel merges.
// Softmax: round-1/2 unconditional rescale (round-7 defer reverted).
// ---------------------------------------------------------------------------
__global__ void __launch_bounds__(256) attn_fwd_kernel(
    const short* __restrict__ qh, const short* __restrict__ kh,
    const short* __restrict__ vt, const unsigned char* __restrict__ keep,
    float* __restrict__ accP, float* __restrict__ mlP)
{
  __shared__ short Klds[2][64*128];   // [buf][kv][d]   16KB each
  __shared__ short Vlds[2][128*64];   // [buf][d][kv]   16KB each
  __shared__ short Plds[4][1024];     // per-wave [16 q][64 kv]  8KB
  const int bid = blockIdx.x;
  const int part = bid >> 9;
  const int inner = bid & 511;
  const int swz = (inner & 7)*64 + (inner >> 3);
  const int h = swz >> 5, qb = swz & 31;
  const int t = threadIdx.x, w = t>>6, l = t&63;
  const int l16 = l&15, lg = l>>4;

  s8v qf[4];
  const int sq0 = qb*64 + w*16;
  const short* qbase = qh + ((size_t)h*2048 + sq0 + l16)*128 + lg*8;
#pragma unroll
  for (int kf=0;kf<4;kf++) qf[kf] = *(const s8v*)(qbase + kf*32);

  f4v acc[8];
  f4v z = {0.f,0.f,0.f,0.f};
#pragma unroll
  for (int d=0;d<8;d++) acc[d] = z;
  float mrow[4], lsum[4];
#pragma unroll
  for (int r=0;r<4;r++){ mrow[r] = -3.0e38f; lsum[r] = 0.f; }

  const unsigned char* keeprow = keep + ((size_t)(h*32) + qb)*32;
  const short* kg0 = kh + (size_t)h*2048*128;
  const short* vg0 = vt + (size_t)h*128*2048;

  unsigned km = 0;
#pragma unroll
  for (int j=0;j<32;j++) km |= ((unsigned)keeprow[j]) << j;
  if (!km) km = 1;                              // defensive (cannot happen)

  // parity split of the COMPACTED kept list -> balanced halves
  unsigned kmp = 0; int idx = 0;
  for (int j=0;j<32;j++){
    if ((km>>j)&1u){
      if ((idx & 1) == part) kmp |= (1u<<j);
      idx++;
    }
  }

  auto stageKV = [&](int buf, int j){
    const char* kg = (const char*)(kg0 + (size_t)(j*64)*128);
    const char* vg = (const char*)(vg0 + j*64);
#pragma unroll
    for (int ii=0;ii<4;ii++){
      int kr = (w*4+ii)*4 + (l>>4);             // K row (256B rows)
      int ks = ((l&15)*16) ^ ((kr&7)<<4);
      gload_lds16(kg + (size_t)kr*256 + ks, (char*)Klds[buf] + (w*4+ii)*1024);
      int vr = (w*4+ii)*8 + (l>>3);             // V row (128B rows, 4096B gstride)
      int vs = ((l&7)*16) ^ ((vr&7)<<4);
      gload_lds16(vg + (size_t)vr*4096 + vs, (char*)Vlds[buf] + (w*4+ii)*1024);
    }
  };

  asm volatile("s_waitcnt vmcnt(0)" ::: "memory");
  int jcur = -1;
  if (kmp){ jcur = (int)__builtin_ctz(kmp); kmp &= kmp-1; stageKV(0, jcur); }
  int cur = 0;

  while (jcur >= 0){
    int jn = -1;
    if (kmp){ jn = (int)__builtin_ctz(kmp); kmp &= kmp-1; }
    if (jn >= 0){
      stageKV(cur^1, jn);
      asm volatile("s_waitcnt vmcnt(8)" ::: "memory");
    } else {
      asm volatile("s_waitcnt vmcnt(0)" ::: "memory");
    }
    __builtin_amdgcn_s_barrier();

    const char* Kl = (const char*)Klds[cur];
    const char* Vl = (const char*)Vlds[cur];

    f4v sacc[4];
#pragma unroll
    for (int nt=0;nt<4;nt++) sacc[nt] = z;
    __builtin_amdgcn_s_setprio(1);
#pragma unroll
    for (int kf=0;kf<4;kf++)
#pragma unroll
      for (int nt=0;nt<4;nt++){
        int kr = nt*16 + l16;
        s8v bfr = *(const s8v*)(Kl + ((kr*256 + kf*64 + lg*16) ^ ((kr&7)<<4)));
        sacc[nt] = __builtin_amdgcn_mfma_f32_16x16x32_bf16(qf[kf], bfr, sacc[nt], 0,0,0);
      }
    __builtin_amdgcn_s_setprio(0);
    const float scl = 0.08838834764831845f;    // 1/sqrt(128)
#pragma unroll
    for (int nt=0;nt<4;nt++) sacc[nt] *= scl;

    // online softmax (unconditional rescale -- round-7 defer reverted)
#pragma unroll
    for (int r=0;r<4;r++){
      float mx = fmaxf(fmaxf(sacc[0][r], sacc[1][r]),
                       fmaxf(sacc[2][r], sacc[3][r]));
      mx = fmaxf(mx, __shfl_xor(mx,1));  mx = fmaxf(mx, __shfl_xor(mx,2));
      mx = fmaxf(mx, __shfl_xor(mx,4));  mx = fmaxf(mx, __shfl_xor(mx,8));
      float mnew = fmaxf(mrow[r], mx);
      float resc = __expf(mrow[r] - mnew);
      mrow[r] = mnew;
      float psum = 0.f;
#pragma unroll
      for (int nt=0;nt<4;nt++){
        float p = __expf(sacc[nt][r] - mnew);
        sacc[nt][r] = p;
        psum += p;
      }
      psum += __shfl_xor(psum,1);  psum += __shfl_xor(psum,2);
      psum += __shfl_xor(psum,4);  psum += __shfl_xor(psum,8);
      lsum[r] = lsum[r]*resc + psum;
#pragma unroll
      for (int dt=0;dt<8;dt++) acc[dt][r] *= resc;
    }

    char* Pl = (char*)Plds[w];
#pragma unroll
    for (int nt=0;nt<4;nt++)
#pragma unroll
      for (int r=0;r<4;r++){
        int pr = lg*4 + r;                       // P row (128B rows)
        *(short*)(Pl + ((pr*128 + nt*32 + l16*2) ^ ((pr&7)<<4))) = f2bf(sacc[nt][r]);
      }
    s8v pa0 = *(const s8v*)(Pl + ((l16*128 +  0 + lg*16) ^ ((l16&7)<<4)));
    s8v pa1 = *(const s8v*)(Pl + ((l16*128 + 64 + lg*16) ^ ((l16&7)<<4)));

    __builtin_amdgcn_s_setprio(1);
#pragma unroll
    for (int kk=0;kk<2;kk++){
      s8v pa = kk ? pa1 : pa0;
#pragma unroll
      for (int dt=0;dt<8;dt++){
        int vr = dt*16 + l16;
        s8v vb = *(const s8v*)(Vl + ((vr*128 + kk*64 + lg*16) ^ ((vr&7)<<4)));
        acc[dt] = __builtin_amdgcn_mfma_f32_16x16x32_bf16(pa, vb, acc[dt], 0,0,0);
      }
    }
    __builtin_amdgcn_s_setprio(0);

    asm volatile("" ::: "memory");
    __builtin_amdgcn_s_barrier();
    cur ^= 1; jcur = jn;
  }

  // ---- partial epilogue: unnormalized acc + (m, l) ----
  const int pb = part*512 + h*32 + qb;
  float* accp = accP + (size_t)pb*8192;
  float* mlp  = mlP  + (size_t)pb*128;
#pragma unroll
  for (int r=0;r<4;r++){
    int row = w*16 + lg*4 + r;
    if (l16 == 0){ mlp[row] = mrow[r]; mlp[64 + row] = lsum[r]; }
#pragma unroll
    for (int dt=0;dt<8;dt++)
      accp[row*128 + dt*16 + l16] = acc[dt][r];
  }
}

// ---------------------------------------------------------------------------
// Flash combine of 2 partials -> bf16 attn_out [S][H*D].
// out = (acc0*e^(m0-m) + acc1*e^(m1-m)) / (l0*e^(m0-m) + l1*e^(m1-m)).
// Empty part has m=-3e38, l=0 -> weight exp underflows to exactly 0.
// ---------------------------------------------------------------------------
__global__ void __launch_bounds__(256) combine_kernel(
    const float* __restrict__ accP, const float* __restrict__ mlP,
    short* __restrict__ out)
{
  int gid = blockIdx.x*256 + threadIdx.x;      // 1,048,576 total
  int dq  = (gid & 31) * 4;
  int rowg = gid >> 5;                          // 32768 rows
  int h = rowg >> 11, s = rowg & 2047;
  int qb = s >> 6, r = s & 63;
  int pb0 = h*32 + qb, pb1 = pb0 + 512;
  float m0 = mlP[pb0*128 + r], l0 = mlP[pb0*128 + 64 + r];
  float m1 = mlP[pb1*128 + r], l1 = mlP[pb1*128 + 64 + r];
  float m = fmaxf(m0, m1);
  float a0 = __expf(m0 - m), a1 = __expf(m1 - m);
  float inv = 1.0f / (l0*a0 + l1*a1);
  f4v v0 = *(const f4v*)(accP + (size_t)pb0*8192 + r*128 + dq);
  f4v v1 = *(const f4v*)(accP + (size_t)pb1*8192 + r*128 + dq);
  s4v ob;
#pragma unroll
  for (int e=0;e<4;e++) ob[e] = f2bf((v0[e]*a0 + v1[e]*a1) * inv);
  *(s4v*)(out + (size_t)s*2048 + h*128 + dq) = ob;
}

// ---------------------------------------------------------------------------
extern "C" void kernel_launch(void* const* d_in, const int* in_sizes, int n_in,
                              void* d_out, int out_size, void* d_ws, size_t ws_size,
                              hipStream_t stream)
{
  (void)in_sizes; (void)n_in; (void)out_size; (void)ws_size;
  const float* x   = (const float*)d_in[0];
  const float* rc  = (const float*)d_in[1];
  const float* rs  = (const float*)d_in[2];
  const void*  sta = d_in[3];
  const float* Wq  = (const float*)d_in[4];
  const float* bq  = (const float*)d_in[5];
  const float* Wk  = (const float*)d_in[6];
  const float* bk  = (const float*)d_in[7];
  const float* Wv  = (const float*)d_in[8];
  const float* bv  = (const float*)d_in[9];
  const float* Wo  = (const float*)d_in[10];
  const float* bo  = (const float*)d_in[11];
  const float* qnw = (const float*)d_in[12];
  const float* knw = (const float*)d_in[13];

  char* ws = (char*)d_ws;
  size_t off = 0;
  auto take = [&](size_t b){ char* p = ws + off; off = (off + b + 255) & ~(size_t)255; return p; };
  short* Xcat  = (short*)take((size_t)2048*4096*2);   // 16.8 MB [hi|lo]
  short* Wcat2 = (short*)take((size_t)4096*4096*2);   // 33.6 MB (dead after QK gemm)
  short* Wt1v  = (short*)take((size_t)2048*2048*2);   //  8.4 MB (dead after V gemm)
  short* Wt1o  = (short*)take((size_t)2048*2048*2);   //  8.4 MB
  float* QKf   = (float*)take((size_t)2048*4096*4);   // 33.6 MB fused Q|K
  short* Vsd   = (short*)take((size_t)2048*2048*2);   //  8.4 MB
  short* Qh    = (short*)take((size_t)NH*2048*128*2); //  8.4 MB
  short* Kh    = (short*)take((size_t)NH*2048*128*2); //  8.4 MB
  float* Qb    = (float*)take((size_t)NH*32*128*4);
  float* Kb    = (float*)take((size_t)NH*32*128*4);
  unsigned char* Keep = (unsigned char*)take(NH*32*32);
  short* AttnO = (short*)QKf;                          // alias: QKf dead after qk_post
  short* Vt    = (short*)((char*)QKf + (size_t)16*1024*1024);  // alias, disjoint
  float* accP  = (float*)Wcat2;                        // alias: 1024*8192*4 = 33.6 MB exact
  float* mlP   = (float*)Wt1v;                         // alias: 512 KB

  conv_x_kernel <<<4096, 256, 0, stream>>>(x, Xcat);
  conv_w3_kernel<<<dim3(32,32,2), 256, 0, stream>>>(Wq, Wk, Wcat2);
  // fused Q+K projection: M=2048, N=4096, logical K=6144 via remap; grid 512
  gemm8_bt<0><<<512, 512, 0, stream>>>(Xcat, 4096, Wcat2, 4096, bq, bk, 2048,
                                       QKf, 4096, 6144, 32,
                                       2048, 2048, 4096, 4096);
  conv_w1_kernel<<<dim3(32,32,2), 256, 0, stream>>>(Wv, Wo, Wt1v, Wt1o);
  gemm8_n64<1><<<512, 512, 0, stream>>>(Xcat, 4096, Wt1v, 2048, bv,
                                        Vsd, 2048, 2048, 32);
  qk_post_kernel<<<dim3(32,16,2), 256, 0, stream>>>(QKf, qnw, knw, rc, rs, Qh, Kh, Qb, Kb);
  v_trans_kernel<<<dim3(32,2,16), 256, 0, stream>>>(Vsd, Vt);
  nabla_mask_kernel<<<dim3(32,16), 64, 0, stream>>>(Qb, Kb, sta, Keep);
  attn_fwd_kernel<<<1024, 256, 0, stream>>>(Qh, Kh, Vt, Keep, accP, mlP);
  combine_kernel<<<4096, 256, 0, stream>>>(accP, mlP, AttnO);
  gemm8_n64<0><<<512, 512, 0, stream>>>((const short*)AttnO, 2048, Wt1o, 2048, bo,
                                        d_out, 2048, 2048, 32);
}